// Round 10
// baseline (270.962 us; speedup 1.0000x reference)
//
#include <hip/hip_runtime.h>
#include <cstdint>

// XLA emits separate mul/add; contraction off by default. Hot paths use
// explicit fmaf()/hw-transcendentals — measured-safe across 7 rounds.
#pragma clang fp contract(off)

#define TSAVES 49
#define SPSAVE 100
#define NB 8192
#define NSTEPS (TSAVES * SPSAVE)   // 4900
#define NTOT (NSTEPS * NB)         // 40140800

typedef float f32x4 __attribute__((ext_vector_type(4)));

__device__ __forceinline__ uint32_t rotl32(uint32_t v, int d) {
  return __builtin_rotateleft32(v, (uint32_t)d);
}

// JAX threefry2x32, 20 rounds.
__device__ __forceinline__ void tf2x32(uint32_t k0, uint32_t k1,
                                       uint32_t x0, uint32_t x1,
                                       uint32_t& o0, uint32_t& o1) {
  uint32_t ks2 = k0 ^ k1 ^ 0x1BD11BDAu;
#define TF_ROUND(r) { x0 += x1; x1 = rotl32(x1, r); x1 ^= x0; }
  x0 += k0; x1 += k1;
  TF_ROUND(13) TF_ROUND(15) TF_ROUND(26) TF_ROUND(6)
  x0 += k1; x1 += ks2 + 1u;
  TF_ROUND(17) TF_ROUND(29) TF_ROUND(16) TF_ROUND(24)
  x0 += ks2; x1 += k0 + 2u;
  TF_ROUND(13) TF_ROUND(15) TF_ROUND(26) TF_ROUND(6)
  x0 += k0; x1 += k1 + 3u;
  TF_ROUND(17) TF_ROUND(29) TF_ROUND(16) TF_ROUND(24)
  x0 += k1; x1 += ks2 + 4u;
  TF_ROUND(13) TF_ROUND(15) TF_ROUND(26) TF_ROUND(6)
  x0 += ks2; x1 += k0 + 5u;
#undef TF_ROUND
  o0 = x0; o1 = x1;
}

// jax.random.split(key(seed)), jax_threefry_partitionable=True (fold-like).
__device__ __forceinline__ void derive_keys(int seed, uint32_t& kn0, uint32_t& kn1,
                                            uint32_t& ku0, uint32_t& ku1) {
  uint64_t s = (uint64_t)(int64_t)seed;
  uint32_t k0 = (uint32_t)(s >> 32);
  uint32_t k1 = (uint32_t)(s & 0xffffffffULL);
  tf2x32(k0, k1, 0u, 0u, kn0, kn1);  // keys[0] = k_noise
  tf2x32(k0, k1, 0u, 1u, ku0, ku1);  // keys[1] = k_u
}

// partitionable random_bits(32): counter = (hi=0, lo=n); bits = y0 ^ y1.
__device__ __forceinline__ uint32_t rand_bits32(uint32_t k0, uint32_t k1, uint32_t n) {
  uint32_t y0, y1;
  tf2x32(k0, k1, 0u, n, y0, y1);
  return y0 ^ y1;
}

// bits -> dw; XLA ErfInv32 (Giles). Branchy tail (execz-skipped ~96% of waves).
__device__ __forceinline__ float bits_to_dw(uint32_t bits) {
#pragma clang fp contract(fast)
  float u01 = __uint_as_float((bits >> 9) | 0x3f800000u) - 1.0f;
  float u = u01 * 2.0f + (-0.99999994f);
  u = fmaxf(-0.99999994f, u);
  float omu2 = 1.0f - u * u;                       // fma(-u,u,1)
  float w = -(__builtin_amdgcn_logf(omu2) * 0.6931472f);  // v_log (log2) * ln2
  float p;
  if (w < 5.0f) {
    float z = w - 2.5f;
    p = 2.81022636e-08f;
    p = 3.43273939e-07f + p * z;
    p = -3.5233877e-06f + p * z;
    p = -4.39150654e-06f + p * z;
    p = 0.00021858087f + p * z;
    p = -0.00125372503f + p * z;
    p = -0.00417768164f + p * z;
    p = 0.246640727f + p * z;
    p = 1.50140941f + p * z;
  } else {
    float z = __builtin_amdgcn_sqrtf(w) - 3.0f;
    p = -0.000200214257f;
    p = 0.000100950558f + p * z;
    p = 0.00134934322f + p * z;
    p = -0.00367342844f + p * z;
    p = 0.00573950773f + p * z;
    p = -0.0076224613f + p * z;
    p = 0.00943887047f + p * z;
    p = 1.00167406f + p * z;
    p = 2.83297682f + p * z;
  }
  float ei = p * u;
  float nrm = 1.41421356f * ei;  // f32(np.sqrt(2))
  return nrm * 0.1f;             // * sqrt(f32(0.01)) == 0.1f exactly
}

__device__ __forceinline__ float clip_param(float x) {
  return fminf(0.99999988f, fmaxf(1e-07f, x));
}

#define GEN_BLOCKS 4096
// 4-step-chunked layout with pvol folded in: noise4[c*NB+b] = dw(4c+k, b) *
// pvol[b], k=0..3. (Known-good: 97 us, VALUBusy ~100% — instruction floor.)
__global__ __launch_bounds__(256) void gen_noise_kernel(const float* __restrict__ cond,
                                                        const int* __restrict__ seedp,
                                                        float* __restrict__ noise) {
  uint64_t sdv = (uint64_t)(int64_t)seedp[0];
  uint32_t k0 = (uint32_t)(sdv >> 32), k1 = (uint32_t)sdv;
  uint32_t kn0, kn1;
  tf2x32(k0, k1, 0u, 0u, kn0, kn1);
  const uint32_t stride = GEN_BLOCKS * 256u;
  for (uint32_t q = blockIdx.x * 256u + threadIdx.x; q < (uint32_t)(NTOT / 4); q += stride) {
    uint32_t c = q >> 13;             // chunk (4 consecutive steps)
    uint32_t b = q & 8191u;           // trajectory
    float pv = clip_param(cond[b * 4 + 3]);
    uint32_t n0 = (4u * c) * (uint32_t)NB + b;
    float4 o;
    o.x = bits_to_dw(rand_bits32(kn0, kn1, n0)) * pv;
    o.y = bits_to_dw(rand_bits32(kn0, kn1, n0 + (uint32_t)NB)) * pv;
    o.z = bits_to_dw(rand_bits32(kn0, kn1, n0 + 2u * (uint32_t)NB)) * pv;
    o.w = bits_to_dw(rand_bits32(kn0, kn1, n0 + 3u * (uint32_t)NB)) * pv;
    *reinterpret_cast<float4*>(noise + (size_t)q * 4) = o;
  }
}

// Streaming summarize + output write for one finished trajectory.
__device__ __forceinline__ void write_out(float* out, int b, float best, int bi,
                                          float sd, float sd2,
                                          uint32_t ku0, uint32_t ku1) {
  uint32_t ub = rand_bits32(ku0, ku1, (uint32_t)b);
  float u = __uint_as_float((ub >> 9) | 0x3f800000u) - 1.0f;
  u = fmaxf(0.0f, u);
  float maxat = ((float)bi + u) / 49.0f;
  float mean = sd / 48.0f;
  float var = sd2 / 48.0f - mean * mean;
  float stdv = sqrtf(fmaxf(var, 0.0f));
  out[b * 3 + 0] = (best  - 0.38f) / 0.14f;
  out[b * 3 + 1] = (maxat - 0.21f) / 0.12f;
  out[b * 3 + 2] = (stdv  - 0.14f) / 0.03f;
}

// 2 independent trajectories per lane: the r0->sqrt->fma chain (~42 cy, the
// round-9-measured floor) of chain B fills chain A's latency shadow.
template <bool FLY>
__global__ __launch_bounds__(64, 1) void sim_kernel(const float* __restrict__ cond,
                                                    const int* __restrict__ seedp,
                                                    const float* __restrict__ noise,
                                                    float* __restrict__ out) {
  const int lane = threadIdx.x;
  const int bA = blockIdx.x * 128 + lane;
  const int bB = bA + 64;

  uint32_t kn0, kn1, ku0, ku1;
  derive_keys(seedp[0], kn0, kn1, ku0, ku1);

  if (FLY) {
    for (int cc = 0; cc < 2; ++cc) {
      const int b = bA + cc * 64;
      float pinf = clip_param(cond[b * 4 + 0]);
      float prec = clip_param(cond[b * 4 + 1]);
      float pmr  = clip_param(cond[b * 4 + 2]);
      float pvol = clip_param(cond[b * 4 + 3]);
      float r0m = pinf / prec;
      float dtmr = 0.01f * pmr;
      float s = 0.99f, i = 0.01f, r0 = r0m;
      float best = -1.0f; int bi = 0;
      float plg = 0.0f, sd = 0.0f, sd2 = 0.0f;
      for (int t = 0; t < TSAVES; ++t) {
#pragma unroll 10
        for (int j = 0; j < SPSAVE; ++j) {
          uint32_t n = (uint32_t)(t * SPSAVE + j) * (uint32_t)NB + (uint32_t)b;
          float dw = bits_to_dw(rand_bits32(kn0, kn1, n));
          float ni = (r0 * prec) * s;
          float nr = prec * i;
          float s_n = s - 0.01f * ni;
          float i_n = i + 0.01f * (ni - nr);
          float r0_n = (r0 + dtmr * (r0m - r0)) + ((sqrtf(fabsf(r0)) * pvol) * dw);
          s = s_n; i = i_n; r0 = r0_n;
        }
        float v = i;
        if (!isfinite(v)) v = 0.0f;
        float x = fmaxf(v, 1e-05f);
        if (x > best) { best = x; bi = t; }
        float lg = logf(x);
        if (t > 0) { float d = lg - plg; sd += d; sd2 += d * d; }
        plg = lg;
      }
      write_out(out, b, best, bi, sd, sd2, ku0, ku1);
    }
    return;
  }

  // ---- dual-chain pipelined path ----
  float pinfA = clip_param(cond[bA * 4 + 0]);
  float precA = clip_param(cond[bA * 4 + 1]);
  float pmrA  = clip_param(cond[bA * 4 + 2]);
  float pinfB = clip_param(cond[bB * 4 + 0]);
  float precB = clip_param(cond[bB * 4 + 1]);
  float pmrB  = clip_param(cond[bB * 4 + 2]);

  const float r0mA = pinfA / precA, dtmrA = 0.01f * pmrA;
  const float r0mB = pinfB / precB, dtmrB = 0.01f * pmrB;
  const float c2A = 0.01f * precA, c3A = 1.0f - c2A, c4A = 1.0f - dtmrA, a4A = dtmrA * r0mA;
  const float c2B = 0.01f * precB, c3B = 1.0f - c2B, c4B = 1.0f - dtmrB, a4B = dtmrB * r0mB;

  float sA = 0.99f, iA = 0.01f, r0A = r0mA;
  float sB = 0.99f, iB = 0.01f, r0B = r0mB;
  float bestA = -1.0f, bestB = -1.0f; int biA = 0, biB = 0;
  float plgA = 0.0f, sdA = 0.0f, sd2A = 0.0f;
  float plgB = 0.0f, sdB = 0.0f, sd2B = 0.0f;

  const f32x4* pA4 = reinterpret_cast<const f32x4*>(noise) + bA;
  const f32x4* pB4 = reinterpret_cast<const f32x4*>(noise) + bB;
  f32x4 qA0[5], qA1[5], qA2[5], qA3[5], qA4[5];
  f32x4 qB0[5], qB1[5], qB2[5], qB3[5], qB4[5];

#define ISSUE5(bufA, bufB, g) { \
    _Pragma("unroll") \
    for (int m = 0; m < 5; ++m) bufA[m] = pA4[(size_t)((g) * 5 + m) * NB]; \
    _Pragma("unroll") \
    for (int m = 0; m < 5; ++m) bufB[m] = pB4[(size_t)((g) * 5 + m) * NB]; \
    __builtin_amdgcn_sched_barrier(0); }
  // 7-op fma step per chain (rounds 8-9 validated); chains independent.
#define CGRP5(bufA, bufB) { \
    _Pragma("unroll") \
    for (int j = 0; j < 20; ++j) { \
      { float vdw = bufA[j >> 2][j & 3]; \
        float sq  = __builtin_amdgcn_sqrtf(fabsf(r0A)); \
        float r0h = fmaf(c4A, r0A, a4A); \
        float rs  = r0A * sA; \
        float r0n = fmaf(sq, vdw, r0h); \
        float s_n = fmaf(-c2A, rs, sA); \
        float i_n = fmaf(c2A, rs, iA * c3A); \
        sA = s_n; iA = i_n; r0A = r0n; } \
      { float vdw = bufB[j >> 2][j & 3]; \
        float sq  = __builtin_amdgcn_sqrtf(fabsf(r0B)); \
        float r0h = fmaf(c4B, r0B, a4B); \
        float rs  = r0B * sB; \
        float r0n = fmaf(sq, vdw, r0h); \
        float s_n = fmaf(-c2B, rs, sB); \
        float i_n = fmaf(c2B, rs, iB * c3B); \
        sB = s_n; iB = i_n; r0B = r0n; } \
    } \
    __builtin_amdgcn_sched_barrier(0); }
#define SAVE(t) { \
    { float v = iA; \
      if (!isfinite(v)) v = 0.0f; \
      float x = fmaxf(v, 1e-05f); \
      if (x > bestA) { bestA = x; biA = (t); } \
      float lg = __builtin_amdgcn_logf(x) * 0.6931472f; \
      if ((t) > 0) { float d = lg - plgA; sdA += d; sd2A += d * d; } \
      plgA = lg; } \
    { float v = iB; \
      if (!isfinite(v)) v = 0.0f; \
      float x = fmaxf(v, 1e-05f); \
      if (x > bestB) { bestB = x; biB = (t); } \
      float lg = __builtin_amdgcn_logf(x) * 0.6931472f; \
      if ((t) > 0) { float d = lg - plgB; sdB += d; sd2B += d * d; } \
      plgB = lg; } }

  ISSUE5(qA0, qB0, 0);
  ISSUE5(qA1, qB1, 1);
  ISSUE5(qA2, qB2, 2);
  ISSUE5(qA3, qB3, 3);
  for (int t = 0; t < TSAVES - 1; ++t) {
    const int G = t * 5;
    ISSUE5(qA4, qB4, G + 4); CGRP5(qA0, qB0);
    ISSUE5(qA0, qB0, G + 5); CGRP5(qA1, qB1);
    ISSUE5(qA1, qB1, G + 6); CGRP5(qA2, qB2);
    ISSUE5(qA2, qB2, G + 7); CGRP5(qA3, qB3);
    ISSUE5(qA3, qB3, G + 8); CGRP5(qA4, qB4);
    SAVE(t);
  }
  // t = 48: groups 240..244; 244 not yet issued (max issued = 243).
  ISSUE5(qA4, qB4, 244); CGRP5(qA0, qB0);
  CGRP5(qA1, qB1);
  CGRP5(qA2, qB2);
  CGRP5(qA3, qB3);
  CGRP5(qA4, qB4);
  SAVE(TSAVES - 1);
#undef ISSUE5
#undef CGRP5
#undef SAVE

  write_out(out, bA, bestA, biA, sdA, sd2A, ku0, ku1);
  write_out(out, bB, bestB, biB, sdB, sd2B, ku0, ku1);
}

extern "C" void kernel_launch(void* const* d_in, const int* in_sizes, int n_in,
                              void* d_out, int out_size, void* d_ws, size_t ws_size,
                              hipStream_t stream) {
  const float* cond = (const float*)d_in[0];
  const int* seedp = (const int*)d_in[1];
  float* out = (float*)d_out;
  float* noise = (float*)d_ws;
  const size_t need = (size_t)NTOT * sizeof(float);
  if (ws_size >= need) {
    gen_noise_kernel<<<GEN_BLOCKS, 256, 0, stream>>>(cond, seedp, noise);
    sim_kernel<false><<<NB / 128, 64, 0, stream>>>(cond, seedp, noise, out);
  } else {
    sim_kernel<true><<<NB / 128, 64, 0, stream>>>(cond, seedp, nullptr, out);
  }
}

// Round 11
// 165.009 us; speedup vs baseline: 1.6421x; 1.6421x over previous
//
#include <hip/hip_runtime.h>
#include <cstdint>

// XLA emits separate mul/add; contraction off by default. Hot paths use
// explicit fmaf()/hw-transcendentals — measured-safe across 8 rounds.
#pragma clang fp contract(off)

#define TSAVES 49
#define SPSAVE 100
#define NB 8192
#define NSTEPS (TSAVES * SPSAVE)   // 4900
#define NTOT (NSTEPS * NB)         // 40140800

typedef float f32x4 __attribute__((ext_vector_type(4)));

__device__ __forceinline__ uint32_t rotl32(uint32_t v, int d) {
  return __builtin_rotateleft32(v, (uint32_t)d);
}

// JAX threefry2x32, 20 rounds.
__device__ __forceinline__ void tf2x32(uint32_t k0, uint32_t k1,
                                       uint32_t x0, uint32_t x1,
                                       uint32_t& o0, uint32_t& o1) {
  uint32_t ks2 = k0 ^ k1 ^ 0x1BD11BDAu;
#define TF_ROUND(r) { x0 += x1; x1 = rotl32(x1, r); x1 ^= x0; }
  x0 += k0; x1 += k1;
  TF_ROUND(13) TF_ROUND(15) TF_ROUND(26) TF_ROUND(6)
  x0 += k1; x1 += ks2 + 1u;
  TF_ROUND(17) TF_ROUND(29) TF_ROUND(16) TF_ROUND(24)
  x0 += ks2; x1 += k0 + 2u;
  TF_ROUND(13) TF_ROUND(15) TF_ROUND(26) TF_ROUND(6)
  x0 += k0; x1 += k1 + 3u;
  TF_ROUND(17) TF_ROUND(29) TF_ROUND(16) TF_ROUND(24)
  x0 += k1; x1 += ks2 + 4u;
  TF_ROUND(13) TF_ROUND(15) TF_ROUND(26) TF_ROUND(6)
  x0 += ks2; x1 += k0 + 5u;
#undef TF_ROUND
  o0 = x0; o1 = x1;
}

// jax.random.split(key(seed)), jax_threefry_partitionable=True (fold-like).
__device__ __forceinline__ void derive_keys(int seed, uint32_t& kn0, uint32_t& kn1,
                                            uint32_t& ku0, uint32_t& ku1) {
  uint64_t s = (uint64_t)(int64_t)seed;
  uint32_t k0 = (uint32_t)(s >> 32);
  uint32_t k1 = (uint32_t)(s & 0xffffffffULL);
  tf2x32(k0, k1, 0u, 0u, kn0, kn1);  // keys[0] = k_noise
  tf2x32(k0, k1, 0u, 1u, ku0, ku1);  // keys[1] = k_u
}

// partitionable random_bits(32): counter = (hi=0, lo=n); bits = y0 ^ y1.
__device__ __forceinline__ uint32_t rand_bits32(uint32_t k0, uint32_t k1, uint32_t n) {
  uint32_t y0, y1;
  tf2x32(k0, k1, 0u, n, y0, y1);
  return y0 ^ y1;
}

// bits -> dw; XLA ErfInv32 (Giles). Branchy tail (execz-skipped ~96% of waves).
__device__ __forceinline__ float bits_to_dw(uint32_t bits) {
#pragma clang fp contract(fast)
  float u01 = __uint_as_float((bits >> 9) | 0x3f800000u) - 1.0f;
  float u = u01 * 2.0f + (-0.99999994f);
  u = fmaxf(-0.99999994f, u);
  float omu2 = 1.0f - u * u;                       // fma(-u,u,1)
  float w = -(__builtin_amdgcn_logf(omu2) * 0.6931472f);  // v_log (log2) * ln2
  float p;
  if (w < 5.0f) {
    float z = w - 2.5f;
    p = 2.81022636e-08f;
    p = 3.43273939e-07f + p * z;
    p = -3.5233877e-06f + p * z;
    p = -4.39150654e-06f + p * z;
    p = 0.00021858087f + p * z;
    p = -0.00125372503f + p * z;
    p = -0.00417768164f + p * z;
    p = 0.246640727f + p * z;
    p = 1.50140941f + p * z;
  } else {
    float z = __builtin_amdgcn_sqrtf(w) - 3.0f;
    p = -0.000200214257f;
    p = 0.000100950558f + p * z;
    p = 0.00134934322f + p * z;
    p = -0.00367342844f + p * z;
    p = 0.00573950773f + p * z;
    p = -0.0076224613f + p * z;
    p = 0.00943887047f + p * z;
    p = 1.00167406f + p * z;
    p = 2.83297682f + p * z;
  }
  float ei = p * u;
  float nrm = 1.41421356f * ei;  // f32(np.sqrt(2))
  return nrm * 0.1f;             // * sqrt(f32(0.01)) == 0.1f exactly
}

__device__ __forceinline__ float clip_param(float x) {
  return fminf(0.99999988f, fmaxf(1e-07f, x));
}

#define GEN_BLOCKS 4096
// 4-step-chunked layout with pvol folded in: noise4[c*NB+b] = dw(4c+k, b) *
// pvol[b], k=0..3. (Known-good: 97 us, VALUBusy ~100% — instruction floor.)
__global__ __launch_bounds__(256) void gen_noise_kernel(const float* __restrict__ cond,
                                                        const int* __restrict__ seedp,
                                                        float* __restrict__ noise) {
  uint64_t sdv = (uint64_t)(int64_t)seedp[0];
  uint32_t k0 = (uint32_t)(sdv >> 32), k1 = (uint32_t)sdv;
  uint32_t kn0, kn1;
  tf2x32(k0, k1, 0u, 0u, kn0, kn1);
  const uint32_t stride = GEN_BLOCKS * 256u;
  for (uint32_t q = blockIdx.x * 256u + threadIdx.x; q < (uint32_t)(NTOT / 4); q += stride) {
    uint32_t c = q >> 13;             // chunk (4 consecutive steps)
    uint32_t b = q & 8191u;           // trajectory
    float pv = clip_param(cond[b * 4 + 3]);
    uint32_t n0 = (4u * c) * (uint32_t)NB + b;
    float4 o;
    o.x = bits_to_dw(rand_bits32(kn0, kn1, n0)) * pv;
    o.y = bits_to_dw(rand_bits32(kn0, kn1, n0 + (uint32_t)NB)) * pv;
    o.z = bits_to_dw(rand_bits32(kn0, kn1, n0 + 2u * (uint32_t)NB)) * pv;
    o.w = bits_to_dw(rand_bits32(kn0, kn1, n0 + 3u * (uint32_t)NB)) * pv;
    *reinterpret_cast<float4*>(noise + (size_t)q * 4) = o;
  }
}

// Streaming summarize + output write for one finished trajectory.
__device__ __forceinline__ void write_out(float* out, int b, float best, int bi,
                                          float sd, float sd2,
                                          uint32_t ku0, uint32_t ku1) {
  uint32_t ub = rand_bits32(ku0, ku1, (uint32_t)b);
  float u = __uint_as_float((ub >> 9) | 0x3f800000u) - 1.0f;
  u = fmaxf(0.0f, u);
  float maxat = ((float)bi + u) / 49.0f;
  float mean = sd / 48.0f;
  float var = sd2 / 48.0f - mean * mean;
  float stdv = sqrtf(fmaxf(var, 0.0f));
  out[b * 3 + 0] = (best  - 0.38f) / 0.14f;
  out[b * 3 + 1] = (maxat - 0.21f) / 0.12f;
  out[b * 3 + 2] = (stdv  - 0.14f) / 0.03f;
}

// Producer/consumer wave split (round-10 lesson: single-wave issue cadence
// ~6 cy/instr is the floor; wall time = per-wave ops/step). Wave 0 runs the
// r0 chain only (~3-4 slots/step) streaming entering-r0 to LDS; wave 1 runs
// s,i (+Horner-4 for i, ~3.5 slots/step) and the summarize. Double-buffered
// 20-step groups, one __syncthreads per group (246 total ~ 5 us).
template <bool FLY>
__global__ __launch_bounds__(128, 1) void sim_kernel(const float* __restrict__ cond,
                                                     const int* __restrict__ seedp,
                                                     const float* __restrict__ noise,
                                                     float* __restrict__ out) {
  __shared__ f32x4 r0b[2][5][64];   // 10 KiB
  const int tid = threadIdx.x;
  const int lane = tid & 63;
  const int wv = tid >> 6;
  const int b = blockIdx.x * 64 + lane;

  uint32_t kn0, kn1, ku0, ku1;
  derive_keys(seedp[0], kn0, kn1, ku0, ku1);

  if (FLY) {
    if (wv == 0) {
      float pinf = clip_param(cond[b * 4 + 0]);
      float prec = clip_param(cond[b * 4 + 1]);
      float pmr  = clip_param(cond[b * 4 + 2]);
      float pvol = clip_param(cond[b * 4 + 3]);
      float r0m = pinf / prec;
      float dtmr = 0.01f * pmr;
      float s = 0.99f, i = 0.01f, r0 = r0m;
      float best = -1.0f; int bi = 0;
      float plg = 0.0f, sd = 0.0f, sd2 = 0.0f;
      for (int t = 0; t < TSAVES; ++t) {
#pragma unroll 10
        for (int j = 0; j < SPSAVE; ++j) {
          uint32_t n = (uint32_t)(t * SPSAVE + j) * (uint32_t)NB + (uint32_t)b;
          float dw = bits_to_dw(rand_bits32(kn0, kn1, n));
          float ni = (r0 * prec) * s;
          float nr = prec * i;
          float s_n = s - 0.01f * ni;
          float i_n = i + 0.01f * (ni - nr);
          float r0_n = (r0 + dtmr * (r0m - r0)) + ((sqrtf(fabsf(r0)) * pvol) * dw);
          s = s_n; i = i_n; r0 = r0_n;
        }
        float v = i;
        if (!isfinite(v)) v = 0.0f;
        float x = fmaxf(v, 1e-05f);
        if (x > best) { best = x; bi = t; }
        float lg = logf(x);
        if (t > 0) { float d = lg - plg; sd += d; sd2 += d * d; }
        plg = lg;
      }
      write_out(out, b, best, bi, sd, sd2, ku0, ku1);
    }
    return;
  }

  if (wv == 0) {
    // ---------------- producer: r0 chain ----------------
    float pinf = clip_param(cond[b * 4 + 0]);
    float prec = clip_param(cond[b * 4 + 1]);
    float pmr  = clip_param(cond[b * 4 + 2]);
    const float r0m  = pinf / prec;
    const float dtmr = 0.01f * pmr;
    const float c4 = 1.0f - dtmr;
    const float a4 = dtmr * r0m;
    float r0 = r0m;

    const f32x4* pb4 = reinterpret_cast<const f32x4*>(noise) + b;
    f32x4 q0[5], q1[5], q2[5], q3[5], q4[5];
#define ISSUE5(buf, g) { \
    _Pragma("unroll") \
    for (int m = 0; m < 5; ++m) buf[m] = pb4[(size_t)((g) * 5 + m) * NB]; \
    __builtin_amdgcn_sched_barrier(0); }
    // One 20-step group: 3-op step (sqrt + 2 fma), write entering-r0 in b128.
#define PROD(qb, g) { \
    _Pragma("unroll") \
    for (int m = 0; m < 5; ++m) { \
      f32x4 w; \
      _Pragma("unroll") \
      for (int e = 0; e < 4; ++e) { \
        w[e] = r0; \
        float vdw = qb[m][e]; \
        float sq  = __builtin_amdgcn_sqrtf(fabsf(r0)); \
        float r0h = fmaf(c4, r0, a4); \
        r0 = fmaf(sq, vdw, r0h); \
      } \
      r0b[(g) & 1][m][lane] = w; \
    } \
    __builtin_amdgcn_sched_barrier(0); }

    ISSUE5(q0, 0);
    ISSUE5(q1, 1);
    ISSUE5(q2, 2);
    ISSUE5(q3, 3);
    ISSUE5(q4, 4);
    PROD(q0, 0);
    __syncthreads();                      // group 0 visible
    for (int t = 0; t < TSAVES - 1; ++t) {
      const int G = t * 5;
      ISSUE5(q0, G + 5); PROD(q1, G + 1); __syncthreads();
      ISSUE5(q1, G + 6); PROD(q2, G + 2); __syncthreads();
      ISSUE5(q2, G + 7); PROD(q3, G + 3); __syncthreads();
      ISSUE5(q3, G + 8); PROD(q4, G + 4); __syncthreads();
      ISSUE5(q4, G + 9); PROD(q0, G + 5); __syncthreads();
    }
    // peel t = 48: consumer processes 240..244; produce 241..244.
    PROD(q1, 241); __syncthreads();
    PROD(q2, 242); __syncthreads();
    PROD(q3, 243); __syncthreads();
    PROD(q4, 244); __syncthreads();
    __syncthreads();
#undef ISSUE5
#undef PROD
  } else {
    // ---------------- consumer: s, i + summarize ----------------
    float prec = clip_param(cond[b * 4 + 1]);
    const float c2 = 0.01f * prec;
    const float c3 = 1.0f - c2;
    const float c32 = c3 * c3;
    const float c3p4 = c32 * c32;
    float s = 0.99f, i = 0.01f;
    float best = -1.0f; int bi = 0;
    float plg = 0.0f, sd = 0.0f, sd2 = 0.0f;

    // i over 4 steps (Horner): i4 = c3^4 i + c2(c3^3 rs0 + c3^2 rs1 + c3 rs2 + rs3)
#define CONS(g) { \
    f32x4 rv[5]; \
    _Pragma("unroll") \
    for (int m = 0; m < 5; ++m) rv[m] = r0b[(g) & 1][m][lane]; \
    _Pragma("unroll") \
    for (int m = 0; m < 5; ++m) { \
      float rs0 = rv[m][0] * s; s = fmaf(-c2, rs0, s); \
      float rs1 = rv[m][1] * s; s = fmaf(-c2, rs1, s); \
      float rs2 = rv[m][2] * s; s = fmaf(-c2, rs2, s); \
      float rs3 = rv[m][3] * s; s = fmaf(-c2, rs3, s); \
      float h = fmaf(c3, rs0, rs1); h = fmaf(c3, h, rs2); h = fmaf(c3, h, rs3); \
      i = fmaf(c3p4, i, c2 * h); \
    } \
    __builtin_amdgcn_sched_barrier(0); }
#define SAVE(t) { \
    float v = i; \
    if (!isfinite(v)) v = 0.0f; \
    float x = fmaxf(v, 1e-05f); \
    if (x > best) { best = x; bi = (t); } \
    float lg = __builtin_amdgcn_logf(x) * 0.6931472f; \
    if ((t) > 0) { float d = lg - plg; sd += d; sd2 += d * d; } \
    plg = lg; }

    __syncthreads();                      // group 0 ready
    for (int t = 0; t < TSAVES - 1; ++t) {
      const int G = t * 5;
      CONS(G + 0); __syncthreads();
      CONS(G + 1); __syncthreads();
      CONS(G + 2); __syncthreads();
      CONS(G + 3); __syncthreads();
      CONS(G + 4); SAVE(t); __syncthreads();
    }
    CONS(240); __syncthreads();
    CONS(241); __syncthreads();
    CONS(242); __syncthreads();
    CONS(243); __syncthreads();
    CONS(244); SAVE(48); __syncthreads();
#undef CONS
#undef SAVE

    write_out(out, b, best, bi, sd, sd2, ku0, ku1);
  }
}

extern "C" void kernel_launch(void* const* d_in, const int* in_sizes, int n_in,
                              void* d_out, int out_size, void* d_ws, size_t ws_size,
                              hipStream_t stream) {
  const float* cond = (const float*)d_in[0];
  const int* seedp = (const int*)d_in[1];
  float* out = (float*)d_out;
  float* noise = (float*)d_ws;
  const size_t need = (size_t)NTOT * sizeof(float);
  if (ws_size >= need) {
    gen_noise_kernel<<<GEN_BLOCKS, 256, 0, stream>>>(cond, seedp, noise);
    sim_kernel<false><<<NB / 64, 128, 0, stream>>>(cond, seedp, noise, out);
  } else {
    sim_kernel<true><<<NB / 64, 128, 0, stream>>>(cond, seedp, nullptr, out);
  }
}